// Round 1
// baseline (6919.502 us; speedup 1.0000x reference)
//
#include <hip/hip_runtime.h>

#define S_LEN 8192
#define NH 16
#define NV 4
#define NB 512

typedef _Float16 h2 __attribute__((ext_vector_type(2)));

// ---------- DPP helpers ----------
template<int R>
__device__ __forceinline__ float rotf(float v) {
    return __int_as_float(__builtin_amdgcn_mov_dpp(__float_as_int(v), 0x120 + R, 0xF, 0xF, true));
}
template<int R>
__device__ __forceinline__ h2 roth(h2 v) {    // row_ror:R on a packed half2 reg
    int i;
    __builtin_memcpy(&i, &v, 4);
    i = __builtin_amdgcn_mov_dpp(i, 0x120 + R, 0xF, 0xF, true);
    h2 o;
    __builtin_memcpy(&o, &i, 4);
    return o;
}
__device__ __forceinline__ float qxor1(float v) {  // quad_perm [1,0,3,2]
    return __int_as_float(__builtin_amdgcn_mov_dpp(__float_as_int(v), 0xB1, 0xF, 0xF, true));
}
__device__ __forceinline__ float qxor2(float v) {  // quad_perm [2,3,0,1]
    return __int_as_float(__builtin_amdgcn_mov_dpp(__float_as_int(v), 0x4E, 0xF, 0xF, true));
}

__device__ __forceinline__ float fsig(float x) {   // mul,exp,add,rcp
    return __builtin_amdgcn_rcpf(1.0f + __expf(-x));
}
__device__ __forceinline__ float frcp(float x) { return __builtin_amdgcn_rcpf(x); }
__device__ __forceinline__ float4 ld4(const float* p) { return *(const float4*)p; }

// Pack (h, rot1(h)) to half2 via v_cvt_pkrtz_f16_f32, bitcast to h2.
__device__ __forceinline__ h2 pkh(float a, float b) {
    auto t = __builtin_amdgcn_cvt_pkrtz(a, b);   // __fp16 ext_vector(2)
    h2 o;
    __builtin_memcpy(&o, &t, 4);
    return o;
}

// hp[k] = packed (h[(j+sgn*2k)&15], h[(j+sgn*(2k+1))&15]) as half2.
// Built from ONE cvt_pkrtz + 8 DPP movs total.
#define FILL_HP16(hp, h)                                      \
    do {                                                      \
        h2 p0_ = pkh((h), rotf<1>(h));                        \
        hp[0] = p0_;                                          \
        hp[1] = roth<2>(p0_);                                 \
        hp[2] = roth<4>(p0_);                                 \
        hp[3] = roth<6>(p0_);                                 \
        hp[4] = roth<8>(p0_);                                 \
        hp[5] = roth<10>(p0_);                                \
        hp[6] = roth<12>(p0_);                                \
        hp[7] = roth<14>(p0_);                                \
    } while (0)

// 16-dot via full-rate v_dot2_f32_f16: 8 dot2 + 1 add, two chains of depth 4.
__device__ __forceinline__ float dotd2(const h2* __restrict__ w, const h2* hp, float start) {
    float a = __builtin_amdgcn_fdot2(w[0], hp[0], start, false);
    float b = __builtin_amdgcn_fdot2(w[1], hp[1], 0.0f, false);
    a = __builtin_amdgcn_fdot2(w[2], hp[2], a, false);
    b = __builtin_amdgcn_fdot2(w[3], hp[3], b, false);
    a = __builtin_amdgcn_fdot2(w[4], hp[4], a, false);
    b = __builtin_amdgcn_fdot2(w[5], hp[5], b, false);
    a = __builtin_amdgcn_fdot2(w[6], hp[6], a, false);
    b = __builtin_amdgcn_fdot2(w[7], hp[7], b, false);
    return a + b;
}

// 64 blocks x 64 threads. Each wave: 8 batch elements = 4 lane-parallel
// (16 lanes each) x 2 register-interleaved chains (A/B). The second chain's
// instructions fill the first chain's dependency-stall slots (latency-bound
// kernel: 1 wave/SIMD, serial recurrence).
__global__ __launch_bounds__(64, 1) void rnn_kernel(
    const float* __restrict__ gt,
    const float* __restrict__ eWih, const float* __restrict__ eWhh,
    const float* __restrict__ ebih, const float* __restrict__ ebhh,
    const float* __restrict__ dWih, const float* __restrict__ dWhh,
    const float* __restrict__ dbih, const float* __restrict__ dbhh,
    const float* __restrict__ oW,  const float* __restrict__ ob,
    float* __restrict__ outs)                 // [NB][S_LEN][4] logit scratch
{
    const int lane = threadIdx.x;
    const int j    = lane & 15;
    const int q    = j & 3;
    const int bA   = blockIdx.x * 8 + (lane >> 4);
    const int bB   = bA + 4;

    // DPP row_ror direction probe (direction-agnostic weight indexing).
    int probe = __builtin_amdgcn_mov_dpp(j, 0x121, 0xF, 0xF, true);
    const int sgn = (probe == ((j + 1) & 15)) ? 1 : -1;

    const float* gA = gt + (size_t)bA * (NV * S_LEN);
    const float* gB = gt + (size_t)bB * (NV * S_LEN);

    // ---------------- encoder weights (paired f16, rotated layout; shared by both chains) ----------------
    h2 ewr[8], ewz[8], ewn[8];
#pragma unroll
    for (int p = 0; p < 8; ++p) {
        int k0 = (j + sgn * (2 * p)) & 15;
        int k1 = (j + sgn * (2 * p + 1)) & 15;
        ewr[p] = (h2){(_Float16)eWhh[(0 * NH + j) * NH + k0], (_Float16)eWhh[(0 * NH + j) * NH + k1]};
        ewz[p] = (h2){(_Float16)eWhh[(1 * NH + j) * NH + k0], (_Float16)eWhh[(1 * NH + j) * NH + k1]};
        ewn[p] = (h2){(_Float16)eWhh[(2 * NH + j) * NH + k0], (_Float16)eWhh[(2 * NH + j) * NH + k1]};
    }
    float exr[NV], exz[NV], exn[NV];
#pragma unroll
    for (int v = 0; v < NV; ++v) {
        exr[v] = eWih[(0 * NH + j) * NV + v];
        exz[v] = eWih[(1 * NH + j) * NV + v];
        exn[v] = eWih[(2 * NH + j) * NV + v];
    }
    const float c_er  = ebih[j] + ebhh[j];
    const float c_ez  = ebih[NH + j] + ebhh[NH + j];
    const float c_ein = ebih[2 * NH + j];
    const float c_ehn = ebhh[2 * NH + j];

    float hA = 0.0f, hB = 0.0f;

    // h' = (1-z)*tanh(inn + r*hn) + z*h, parallel-blend form (R4).
    auto gru = [&](float& h, float ar, float az, float hn, float inn) {
        float r  = fsig(ar);
        float z  = fsig(az);
        float t2 = fmaf(-2.0f, z, 2.0f);
        float tb = fmaf(z, h, z - 1.0f);
        float y  = fmaf(r, hn, inn);
        float w2 = frcp(1.0f + __expf(-2.0f * y));
        h = fmaf(w2, t2, tb);
    };

    auto estep2 = [&](float a0, float a1, float a2, float a3,
                      float b0, float b1, float b2, float b3) {
        float xrA = fmaf(exr[0], a0, fmaf(exr[1], a1, fmaf(exr[2], a2, fmaf(exr[3], a3, c_er))));
        float xzA = fmaf(exz[0], a0, fmaf(exz[1], a1, fmaf(exz[2], a2, fmaf(exz[3], a3, c_ez))));
        float xnA = fmaf(exn[0], a0, fmaf(exn[1], a1, fmaf(exn[2], a2, fmaf(exn[3], a3, c_ein))));
        float xrB = fmaf(exr[0], b0, fmaf(exr[1], b1, fmaf(exr[2], b2, fmaf(exr[3], b3, c_er))));
        float xzB = fmaf(exz[0], b0, fmaf(exz[1], b1, fmaf(exz[2], b2, fmaf(exz[3], b3, c_ez))));
        float xnB = fmaf(exn[0], b0, fmaf(exn[1], b1, fmaf(exn[2], b2, fmaf(exn[3], b3, c_ein))));
        h2 hpA[8], hpB[8];
        FILL_HP16(hpA, hA);
        FILL_HP16(hpB, hB);
        float arA = dotd2(ewr, hpA, xrA);
        float arB = dotd2(ewr, hpB, xrB);
        float azA = dotd2(ewz, hpA, xzA);
        float azB = dotd2(ewz, hpB, xzB);
        float hnA = dotd2(ewn, hpA, c_ehn);
        float hnB = dotd2(ewn, hpB, c_ehn);
        gru(hA, arA, azA, hnA, xnA);
        gru(hB, arB, azB, hnB, xnB);
    };

    // ---------------- encoder loop (both chains interleaved) ----------------
    {
        float4 A0 = ld4(gA + 0 * S_LEN), A1 = ld4(gA + 1 * S_LEN),
               A2 = ld4(gA + 2 * S_LEN), A3 = ld4(gA + 3 * S_LEN);
        float4 E0 = ld4(gB + 0 * S_LEN), E1 = ld4(gB + 1 * S_LEN),
               E2 = ld4(gB + 2 * S_LEN), E3 = ld4(gB + 3 * S_LEN);
        float4 B0 = ld4(gA + 0 * S_LEN + 4), B1 = ld4(gA + 1 * S_LEN + 4),
               B2 = ld4(gA + 2 * S_LEN + 4), B3 = ld4(gA + 3 * S_LEN + 4);
        float4 F0 = ld4(gB + 0 * S_LEN + 4), F1 = ld4(gB + 1 * S_LEN + 4),
               F2 = ld4(gB + 2 * S_LEN + 4), F3 = ld4(gB + 3 * S_LEN + 4);
        for (int t = 0; t < S_LEN; t += 8) {
            estep2(A0.x, A1.x, A2.x, A3.x, E0.x, E1.x, E2.x, E3.x);
            estep2(A0.y, A1.y, A2.y, A3.y, E0.y, E1.y, E2.y, E3.y);
            estep2(A0.z, A1.z, A2.z, A3.z, E0.z, E1.z, E2.z, E3.z);
            estep2(A0.w, A1.w, A2.w, A3.w, E0.w, E1.w, E2.w, E3.w);
            int ta = t + 8;  if (ta > S_LEN - 4) ta = S_LEN - 4;
            A0 = ld4(gA + 0 * S_LEN + ta); A1 = ld4(gA + 1 * S_LEN + ta);
            A2 = ld4(gA + 2 * S_LEN + ta); A3 = ld4(gA + 3 * S_LEN + ta);
            E0 = ld4(gB + 0 * S_LEN + ta); E1 = ld4(gB + 1 * S_LEN + ta);
            E2 = ld4(gB + 2 * S_LEN + ta); E3 = ld4(gB + 3 * S_LEN + ta);
            estep2(B0.x, B1.x, B2.x, B3.x, F0.x, F1.x, F2.x, F3.x);
            estep2(B0.y, B1.y, B2.y, B3.y, F0.y, F1.y, F2.y, F3.y);
            estep2(B0.z, B1.z, B2.z, B3.z, F0.z, F1.z, F2.z, F3.z);
            estep2(B0.w, B1.w, B2.w, B3.w, F0.w, F1.w, F2.w, F3.w);
            int tb2 = t + 12; if (tb2 > S_LEN - 4) tb2 = S_LEN - 4;
            B0 = ld4(gA + 0 * S_LEN + tb2); B1 = ld4(gA + 1 * S_LEN + tb2);
            B2 = ld4(gA + 2 * S_LEN + tb2); B3 = ld4(gA + 3 * S_LEN + tb2);
            F0 = ld4(gB + 0 * S_LEN + tb2); F1 = ld4(gB + 1 * S_LEN + tb2);
            F2 = ld4(gB + 2 * S_LEN + tb2); F3 = ld4(gB + 3 * S_LEN + tb2);
        }
    }

    // ---------------- decoder weights (shared by both chains) ----------------
    h2 dwr[8], dwz[8], dwn[8], ow2[8];
#pragma unroll
    for (int p = 0; p < 8; ++p) {
        int k0 = (j + sgn * (2 * p)) & 15;
        int k1 = (j + sgn * (2 * p + 1)) & 15;
        dwr[p] = (h2){(_Float16)dWhh[(0 * NH + j) * NH + k0], (_Float16)dWhh[(0 * NH + j) * NH + k1]};
        dwz[p] = (h2){(_Float16)dWhh[(1 * NH + j) * NH + k0], (_Float16)dWhh[(1 * NH + j) * NH + k1]};
        dwn[p] = (h2){(_Float16)dWhh[(2 * NH + j) * NH + k0], (_Float16)dWhh[(2 * NH + j) * NH + k1]};
        ow2[p] = (h2){(_Float16)oW[q * NH + k0], (_Float16)oW[q * NH + k1]};
    }
    const float bR  = dbih[j] + dbhh[j];
    const float bZ  = dbih[NH + j] + dbhh[NH + j];
    const float bNi = dbih[2 * NH + j];
    const float bHn = dbhh[2 * NH + j];
    // per-class one-hot constants, REGISTER order m (class = m ^ q); bNi folded into KN:
    float KRr[NV], KZr[NV], KNr[NV];
#pragma unroll
    for (int m = 0; m < NV; ++m) {
        int c = m ^ q;
        KRr[m] = dWih[(0 * NH + j) * NV + c];
        KZr[m] = dWih[(1 * NH + j) * NV + c];
        KNr[m] = bNi + dWih[(2 * NH + j) * NV + c];
    }
    const float obq = ob[q];

    int oidxA = (bA << 15) + q;     // (b*S_LEN + 0)*4 + q  -- [B][S][4] layout
    int oidxB = (bB << 15) + q;
    const bool storer = (j < 4);    // quad 0 of each row stores out[0..3]

    auto dstep2 = [&]() {
        h2 hpA[8], hpB[8];
        FILL_HP16(hpA, hA);
        FILL_HP16(hpB, hB);
        float arA = dotd2(dwr, hpA, bR);
        float arB = dotd2(dwr, hpB, bR);
        float azA = dotd2(dwz, hpA, bZ);
        float azB = dotd2(dwz, hpB, bZ);
        float hnA = dotd2(dwn, hpA, bHn);
        float hnB = dotd2(dwn, hpB, bHn);
        float oaA = dotd2(ow2, hpA, obq);        // out[q] of step t-1
        float oaB = dotd2(ow2, hpB, obq);
        if (storer) {
            outs[oidxA] = oaA;
            outs[oidxB] = oaB;
        }
        oidxA += 4; oidxB += 4;
        // argmax-select, chain A
        float obA = qxor1(oaA), ocA = qxor2(oaA);
        float odA = qxor2(obA);
        bool cA1 = obA > oaA;  float mA1 = fmaxf(oaA, obA);
        bool cB1 = odA > ocA;  float mB1 = fmaxf(ocA, odA);
        bool hi1 = mB1 > mA1;
        float KRA = hi1 ? (cB1 ? KRr[3] : KRr[2]) : (cA1 ? KRr[1] : KRr[0]);
        float KZA = hi1 ? (cB1 ? KZr[3] : KZr[2]) : (cA1 ? KZr[1] : KZr[0]);
        float KNA = hi1 ? (cB1 ? KNr[3] : KNr[2]) : (cA1 ? KNr[1] : KNr[0]);
        // argmax-select, chain B
        float obB = qxor1(oaB), ocB = qxor2(oaB);
        float odB = qxor2(obB);
        bool cA2 = obB > oaB;  float mA2 = fmaxf(oaB, obB);
        bool cB2 = odB > ocB;  float mB2 = fmaxf(ocB, odB);
        bool hi2 = mB2 > mA2;
        float KRB = hi2 ? (cB2 ? KRr[3] : KRr[2]) : (cA2 ? KRr[1] : KRr[0]);
        float KZB = hi2 ? (cB2 ? KZr[3] : KZr[2]) : (cA2 ? KZr[1] : KZr[0]);
        float KNB = hi2 ? (cB2 ? KNr[3] : KNr[2]) : (cA2 ? KNr[1] : KNr[0]);
        gru(hA, arA + KRA, azA + KZA, hnA, KNA);
        gru(hB, arB + KRB, azB + KZB, hnB, KNB);
    };

    // ---------------- decoder loop (no gt reads) ----------------
    {
        // t = 0: x0 = zeros, no previous logits
        h2 hpA[8], hpB[8];
        FILL_HP16(hpA, hA);
        FILL_HP16(hpB, hB);
        float arA = dotd2(dwr, hpA, bR);
        float arB = dotd2(dwr, hpB, bR);
        float azA = dotd2(dwz, hpA, bZ);
        float azB = dotd2(dwz, hpB, bZ);
        float hnA = dotd2(dwn, hpA, bHn);
        float hnB = dotd2(dwn, hpB, bHn);
        gru(hA, arA, azA, hnA, bNi);
        gru(hB, arB, azB, hnB, bNi);
    }
    for (int u = 0; u < S_LEN - 4; u += 4) {     // t = 1..8188
        dstep2(); dstep2(); dstep2(); dstep2();
    }
    dstep2(); dstep2(); dstep2();                // t = 8189..8191

    // tail: logits of final step (t = S-1)
    {
        h2 hpA[8], hpB[8];
        FILL_HP16(hpA, hA);
        FILL_HP16(hpB, hB);
        float oaA = dotd2(ow2, hpA, obq);
        float oaB = dotd2(ow2, hpB, obq);
        if (storer) {
            outs[oidxA] = oaA;
            outs[oidxB] = oaB;
        }
    }
}

// Epilogue: NLL over all (b,t) from stored logits + gt targets; zero the scratch
// (restores the required all-zero output_batch). 4096 blocks x 1024 threads.
__global__ __launch_bounds__(1024) void loss_kernel(
    const float* __restrict__ gt, float* __restrict__ outs, float* __restrict__ loss)
{
    int tid = blockIdx.x * 1024 + threadIdx.x;   // over NB*S_LEN
    int t = tid & (S_LEN - 1);
    int b = tid >> 13;
    float4 o = *(const float4*)(outs + (size_t)tid * 4);
    const float* g = gt + (size_t)b * (NV * S_LEN) + t;
    float p0 = g[0], p1 = g[S_LEN], p2 = g[2 * S_LEN], p3 = g[3 * S_LEN];
    int tg = (p1 > p0) ? 1 : 0;  float bm = fmaxf(p0, p1);
    tg = (p2 > bm) ? 2 : tg;     bm = fmaxf(p2, bm);
    tg = (p3 > bm) ? 3 : tg;
    float vt = (tg & 1) ? ((tg & 2) ? o.w : o.y) : ((tg & 2) ? o.z : o.x);
    float mx = fmaxf(fmaxf(o.x, o.y), fmaxf(o.z, o.w));
    float ss = __expf(o.x - mx) + __expf(o.y - mx) + __expf(o.z - mx) + __expf(o.w - mx);
    float v  = (mx - vt) + __logf(ss);
    *(float4*)(outs + (size_t)tid * 4) = make_float4(0.f, 0.f, 0.f, 0.f);
#pragma unroll
    for (int d = 1; d < 64; d <<= 1) v += __shfl_xor(v, d, 64);
    __shared__ float sm[16];
    int w = threadIdx.x >> 6;
    if ((threadIdx.x & 63) == 0) sm[w] = v;
    __syncthreads();
    if (threadIdx.x < 16) {
        float s = sm[threadIdx.x];
#pragma unroll
        for (int d = 1; d < 16; d <<= 1) s += __shfl_xor(s, d, 64);
        if (threadIdx.x == 0) atomicAdd(loss, s * (1.0f / NB));
    }
}

extern "C" void kernel_launch(void* const* d_in, const int* in_sizes, int n_in,
                              void* d_out, int out_size, void* d_ws, size_t ws_size,
                              hipStream_t stream) {
    (void)in_sizes; (void)n_in; (void)d_ws; (void)ws_size; (void)out_size;
    const float* gt   = (const float*)d_in[0];
    const float* eWih = (const float*)d_in[1];
    const float* eWhh = (const float*)d_in[2];
    const float* ebih = (const float*)d_in[3];
    const float* ebhh = (const float*)d_in[4];
    const float* dWih = (const float*)d_in[5];
    const float* dWhh = (const float*)d_in[6];
    const float* dbih = (const float*)d_in[7];
    const float* dbhh = (const float*)d_in[8];
    const float* oW   = (const float*)d_in[9];
    const float* ob   = (const float*)d_in[10];

    float* out  = (float*)d_out;       // out[0] = loss
    float* outs = out + 1;             // [NB][S_LEN][4] logit scratch == output_batch region
    (void)hipMemsetAsync(d_out, 0, sizeof(float), stream);   // zero loss only
    rnn_kernel<<<NB / 8, 64, 0, stream>>>(gt, eWih, eWhh, ebih, ebhh,
                                          dWih, dWhh, dbih, dbhh, oW, ob, outs);
    loss_kernel<<<(NB * S_LEN) / 1024, 1024, 0, stream>>>(gt, outs, out);
}

// Round 2
// 3328.801 us; speedup vs baseline: 2.0787x; 2.0787x over previous
//
#include <hip/hip_runtime.h>

#define S_LEN 8192
#define NH 16
#define NV 4
#define NB 512

typedef _Float16 h2 __attribute__((ext_vector_type(2)));

// ---------- DPP helpers ----------
template<int R>
__device__ __forceinline__ float rotf(float v) {
    return __int_as_float(__builtin_amdgcn_mov_dpp(__float_as_int(v), 0x120 + R, 0xF, 0xF, true));
}
template<int R>
__device__ __forceinline__ h2 roth(h2 v) {    // row_ror:R on a packed half2 reg
    int i;
    __builtin_memcpy(&i, &v, 4);
    i = __builtin_amdgcn_mov_dpp(i, 0x120 + R, 0xF, 0xF, true);
    h2 o;
    __builtin_memcpy(&o, &i, 4);
    return o;
}
__device__ __forceinline__ float qxor1(float v) {  // quad_perm [1,0,3,2]
    return __int_as_float(__builtin_amdgcn_mov_dpp(__float_as_int(v), 0xB1, 0xF, 0xF, true));
}
__device__ __forceinline__ float qxor2(float v) {  // quad_perm [2,3,0,1]
    return __int_as_float(__builtin_amdgcn_mov_dpp(__float_as_int(v), 0x4E, 0xF, 0xF, true));
}

__device__ __forceinline__ float fsig(float x) {   // mul,exp,add,rcp
    return __builtin_amdgcn_rcpf(1.0f + __expf(-x));
}
__device__ __forceinline__ float frcp(float x) { return __builtin_amdgcn_rcpf(x); }
__device__ __forceinline__ float4 ld4(const float* p) { return *(const float4*)p; }

// Pack (h, rot1(h)) to half2 via v_cvt_pkrtz_f16_f32, bitcast to h2.
__device__ __forceinline__ h2 pkh(float a, float b) {
    auto t = __builtin_amdgcn_cvt_pkrtz(a, b);   // __fp16 ext_vector(2)
    h2 o;
    __builtin_memcpy(&o, &t, 4);
    return o;
}

// lane i <-> lane i+32 exchange: one v_permlane32_swap_b32 (gfx950; VALU-rate).
// After the swap with a=b=v: a = {v.lo, v.lo}, b = {v.hi, v.hi}.
__device__ __forceinline__ float xor32f(float v, bool isLo) {
    float a = v, b = v;
    asm("v_permlane32_swap_b32 %0, %1" : "+v"(a), "+v"(b));
    return isLo ? b : a;
}

// hp[k] = packed (h[(j+sgn*2k)&15], h[(j+sgn*(2k+1))&15]) as half2.
#define FILL_HP16(hp, h)                                      \
    do {                                                      \
        h2 p0_ = pkh((h), rotf<1>(h));                        \
        hp[0] = p0_;                                          \
        hp[1] = roth<2>(p0_);                                 \
        hp[2] = roth<4>(p0_);                                 \
        hp[3] = roth<6>(p0_);                                 \
        hp[4] = roth<8>(p0_);                                 \
        hp[5] = roth<10>(p0_);                                \
        hp[6] = roth<12>(p0_);                                \
        hp[7] = roth<14>(p0_);                                \
    } while (0)

// 16-dot via v_dot2_f32_f16: 8 dot2 + 1 add, two chains of depth 4.
__device__ __forceinline__ float dotd2(const h2* __restrict__ w, const h2* hp, float start) {
    float a = __builtin_amdgcn_fdot2(w[0], hp[0], start, false);
    float b = __builtin_amdgcn_fdot2(w[1], hp[1], 0.0f, false);
    a = __builtin_amdgcn_fdot2(w[2], hp[2], a, false);
    b = __builtin_amdgcn_fdot2(w[3], hp[3], b, false);
    a = __builtin_amdgcn_fdot2(w[4], hp[4], a, false);
    b = __builtin_amdgcn_fdot2(w[5], hp[5], b, false);
    a = __builtin_amdgcn_fdot2(w[6], hp[6], a, false);
    b = __builtin_amdgcn_fdot2(w[7], hp[7], b, false);
    return a + b;
}

// ======================= ENCODER =======================
// 128 blocks x 64 threads; 4 elements/wave (round-0 structure, verbatim).
// Writes final hidden state to hsc[b*16+j].
__global__ __launch_bounds__(64, 1) void enc_kernel(
    const float* __restrict__ gt,
    const float* __restrict__ eWih, const float* __restrict__ eWhh,
    const float* __restrict__ ebih, const float* __restrict__ ebhh,
    float* __restrict__ hsc)
{
    const int lane = threadIdx.x;
    const int j    = lane & 15;
    const int b    = blockIdx.x * 4 + (lane >> 4);

    int probe = __builtin_amdgcn_mov_dpp(j, 0x121, 0xF, 0xF, true);
    const int sgn = (probe == ((j + 1) & 15)) ? 1 : -1;

    const float* gb = gt + (size_t)b * (NV * S_LEN);

    h2 ewr[8], ewz[8], ewn[8];
#pragma unroll
    for (int p = 0; p < 8; ++p) {
        int k0 = (j + sgn * (2 * p)) & 15;
        int k1 = (j + sgn * (2 * p + 1)) & 15;
        ewr[p] = (h2){(_Float16)eWhh[(0 * NH + j) * NH + k0], (_Float16)eWhh[(0 * NH + j) * NH + k1]};
        ewz[p] = (h2){(_Float16)eWhh[(1 * NH + j) * NH + k0], (_Float16)eWhh[(1 * NH + j) * NH + k1]};
        ewn[p] = (h2){(_Float16)eWhh[(2 * NH + j) * NH + k0], (_Float16)eWhh[(2 * NH + j) * NH + k1]};
    }
    float exr[NV], exz[NV], exn[NV];
#pragma unroll
    for (int v = 0; v < NV; ++v) {
        exr[v] = eWih[(0 * NH + j) * NV + v];
        exz[v] = eWih[(1 * NH + j) * NV + v];
        exn[v] = eWih[(2 * NH + j) * NV + v];
    }
    const float c_er  = ebih[j] + ebhh[j];
    const float c_ez  = ebih[NH + j] + ebhh[NH + j];
    const float c_ein = ebih[2 * NH + j];
    const float c_ehn = ebhh[2 * NH + j];

    float h = 0.0f;

    auto gru = [&](float ar, float az, float hn, float inn) {
        float r  = fsig(ar);
        float z  = fsig(az);
        float t2 = fmaf(-2.0f, z, 2.0f);
        float tb = fmaf(z, h, z - 1.0f);
        float y  = fmaf(r, hn, inn);
        float w2 = frcp(1.0f + __expf(-2.0f * y));
        h = fmaf(w2, t2, tb);
    };

    auto estep = [&](float x0, float x1, float x2, float x3) {
        float xr = fmaf(exr[0], x0, fmaf(exr[1], x1, fmaf(exr[2], x2, fmaf(exr[3], x3, c_er))));
        float xz = fmaf(exz[0], x0, fmaf(exz[1], x1, fmaf(exz[2], x2, fmaf(exz[3], x3, c_ez))));
        float xn = fmaf(exn[0], x0, fmaf(exn[1], x1, fmaf(exn[2], x2, fmaf(exn[3], x3, c_ein))));
        h2 hp[8];
        FILL_HP16(hp, h);
        float ar = dotd2(ewr, hp, xr);
        float az = dotd2(ewz, hp, xz);
        float hn = dotd2(ewn, hp, c_ehn);
        gru(ar, az, hn, xn);
    };

    {
        float4 A0 = ld4(gb + 0 * S_LEN), A1 = ld4(gb + 1 * S_LEN),
               A2 = ld4(gb + 2 * S_LEN), A3 = ld4(gb + 3 * S_LEN);
        float4 B0 = ld4(gb + 0 * S_LEN + 4), B1 = ld4(gb + 1 * S_LEN + 4),
               B2 = ld4(gb + 2 * S_LEN + 4), B3 = ld4(gb + 3 * S_LEN + 4);
        for (int t = 0; t < S_LEN; t += 8) {
            estep(A0.x, A1.x, A2.x, A3.x);
            estep(A0.y, A1.y, A2.y, A3.y);
            estep(A0.z, A1.z, A2.z, A3.z);
            estep(A0.w, A1.w, A2.w, A3.w);
            int ta = t + 8;  if (ta > S_LEN - 4) ta = S_LEN - 4;
            A0 = ld4(gb + 0 * S_LEN + ta); A1 = ld4(gb + 1 * S_LEN + ta);
            A2 = ld4(gb + 2 * S_LEN + ta); A3 = ld4(gb + 3 * S_LEN + ta);
            estep(B0.x, B1.x, B2.x, B3.x);
            estep(B0.y, B1.y, B2.y, B3.y);
            estep(B0.z, B1.z, B2.z, B3.z);
            estep(B0.w, B1.w, B2.w, B3.w);
            int tb2 = t + 12; if (tb2 > S_LEN - 4) tb2 = S_LEN - 4;
            B0 = ld4(gb + 0 * S_LEN + tb2); B1 = ld4(gb + 1 * S_LEN + tb2);
            B2 = ld4(gb + 2 * S_LEN + tb2); B3 = ld4(gb + 3 * S_LEN + tb2);
        }
    }

    hsc[(size_t)b * NH + j] = h;
}

// ======================= DECODER =======================
// 256 blocks x 64 threads; 2 elements/wave. Each element owns two 16-lane
// rows: "lo" row (lanes 0-31 half) computes the r-gate and n-gate dots,
// "hi" row (lanes 32-63 half) computes the z-gate and out dots. Rows
// exchange results via v_permlane32_swap_b32 (lane i <-> i+32).
// Per-step instruction count ~67 vs 83 in the 4-elem layout; wall time of
// this phase ~ instr/step (per-wave issue-throughput-bound regime).
// Arithmetic is bit-identical to the round-0 decoder.
__global__ __launch_bounds__(64, 1) void dec_kernel(
    const float* __restrict__ dWih, const float* __restrict__ dWhh,
    const float* __restrict__ dbih, const float* __restrict__ dbhh,
    const float* __restrict__ oW,  const float* __restrict__ ob,
    const float* __restrict__ hsc,
    float* __restrict__ outs)                 // [NB][S_LEN][4] logit scratch
{
    const int lane = threadIdx.x;
    const int j    = lane & 15;
    const int q    = j & 3;
    const int row  = lane >> 4;               // 0,1 = lo role; 2,3 = hi role
    const bool isLo = (lane < 32);
    const int b    = blockIdx.x * 2 + (row & 1);

    int probe = __builtin_amdgcn_mov_dpp(j, 0x121, 0xF, 0xF, true);
    const int sgn = (probe == ((j + 1) & 15)) ? 1 : -1;

    // wA: lo -> dWhh r-rows, hi -> dWhh z-rows.
    // wB: lo -> dWhh n-rows, hi -> oW out-rows (by q, 4x replicated over j>>2).
    const int gA = isLo ? 0 : 1;
    h2 wA[8], wB[8];
#pragma unroll
    for (int p = 0; p < 8; ++p) {
        int k0 = (j + sgn * (2 * p)) & 15;
        int k1 = (j + sgn * (2 * p + 1)) & 15;
        wA[p] = (h2){(_Float16)dWhh[(gA * NH + j) * NH + k0],
                     (_Float16)dWhh[(gA * NH + j) * NH + k1]};
        float w0 = isLo ? dWhh[(2 * NH + j) * NH + k0] : oW[q * NH + k0];
        float w1 = isLo ? dWhh[(2 * NH + j) * NH + k1] : oW[q * NH + k1];
        wB[p] = (h2){(_Float16)w0, (_Float16)w1};
    }
    const float bR  = dbih[j] + dbhh[j];
    const float bZ  = dbih[NH + j] + dbhh[NH + j];
    const float bNi = dbih[2 * NH + j];
    const float bHn = dbhh[2 * NH + j];
    const float biasA  = isLo ? bR  : bZ;     // dot-A start (bias only; K added post-dot)
    const float startB = isLo ? bHn : ob[q];  // dot-B start
    // per-class one-hot x-terms, REGISTER order m (class = m ^ q):
    // SA = x-term for this row's A-gate (r for lo, z for hi);
    // KN = bNi + x-term of n-gate — role-independent (same j => same value
    // in both partner rows, so y/w2/h' stay identical across partners).
    float SA[NV], KN[NV];
#pragma unroll
    for (int m = 0; m < NV; ++m) {
        int c = m ^ q;
        SA[m] = dWih[(gA * NH + j) * NV + c];
        KN[m] = bNi + dWih[(2 * NH + j) * NV + c];
    }

    float h = hsc[(size_t)b * NH + j];

    int oidx = (b << 15) + q;                 // (b*S_LEN + 0)*4 + q
    const bool storer = isLo && (j < 4);      // rows 0,1: one store per element

    auto dstep = [&]() {
        h2 hp[8];
        FILL_HP16(hp, h);
        float aA  = dotd2(wA, hp, biasA);     // lo: ar (pre-K) | hi: az (pre-K)
        float aB  = dotd2(wB, hp, startB);    // lo: hn         | hi: oa
        float aBP = xor32f(aB, isLo);
        float hn  = isLo ? aB  : aBP;
        float oa  = isLo ? aBP : aB;
        if (storer) outs[oidx] = oa;          // logits of step t-1
        oidx += 4;
        // argmax over the quad (identical comparisons to round-0)
        float ob_ = qxor1(oa);                // out[q^1]
        float oc_ = qxor2(oa);                // out[q^2]
        float od_ = qxor2(ob_);               // out[q^3]
        bool cA = ob_ > oa;  float mA = fmaxf(oa, ob_);
        bool cB = od_ > oc_; float mB = fmaxf(oc_, od_);
        bool hi_ = mB > mA;
        float KA  = hi_ ? (cB ? SA[3] : SA[2]) : (cA ? SA[1] : SA[0]);
        float KN_ = hi_ ? (cB ? KN[3] : KN[2]) : (cA ? KN[1] : KN[0]);
        float sg  = fsig(aA + KA);            // lo: r | hi: z
        float sgP = xor32f(sg, isLo);
        float r   = isLo ? sg  : sgP;
        float z   = isLo ? sgP : sg;
        float y   = fmaf(r, hn, KN_);
        float w2  = frcp(1.0f + __expf(-2.0f * y));
        float t2  = fmaf(-2.0f, z, 2.0f);
        float tb  = fmaf(z, h, z - 1.0f);
        h = fmaf(w2, t2, tb);
    };

    // t = 0: x0 = zeros — no K terms, no store, no argmax
    {
        h2 hp[8];
        FILL_HP16(hp, h);
        float aA  = dotd2(wA, hp, biasA);
        float aB  = dotd2(wB, hp, startB);
        float aBP = xor32f(aB, isLo);
        float hn  = isLo ? aB : aBP;
        float sg  = fsig(aA);
        float sgP = xor32f(sg, isLo);
        float r   = isLo ? sg  : sgP;
        float z   = isLo ? sgP : sg;
        float y   = fmaf(r, hn, bNi);
        float w2  = frcp(1.0f + __expf(-2.0f * y));
        float t2  = fmaf(-2.0f, z, 2.0f);
        float tb  = fmaf(z, h, z - 1.0f);
        h = fmaf(w2, t2, tb);
    }
    for (int u = 0; u < S_LEN - 4; u += 4) {  // t = 1..8188
        dstep(); dstep(); dstep(); dstep();
    }
    dstep(); dstep(); dstep();                // t = 8189..8191

    // tail: logits of final step (t = S-1)
    {
        h2 hp[8];
        FILL_HP16(hp, h);
        float aB  = dotd2(wB, hp, startB);
        float aBP = xor32f(aB, isLo);
        float oa  = isLo ? aBP : aB;
        if (storer) outs[oidx] = oa;
    }
}

// Epilogue: NLL over all (b,t) from stored logits + gt targets; zero the scratch
// (restores the required all-zero output_batch). 4096 blocks x 1024 threads.
__global__ __launch_bounds__(1024) void loss_kernel(
    const float* __restrict__ gt, float* __restrict__ outs, float* __restrict__ loss)
{
    int tid = blockIdx.x * 1024 + threadIdx.x;   // over NB*S_LEN
    int t = tid & (S_LEN - 1);
    int b = tid >> 13;
    float4 o = *(const float4*)(outs + (size_t)tid * 4);
    const float* g = gt + (size_t)b * (NV * S_LEN) + t;
    float p0 = g[0], p1 = g[S_LEN], p2 = g[2 * S_LEN], p3 = g[3 * S_LEN];
    int tg = (p1 > p0) ? 1 : 0;  float bm = fmaxf(p0, p1);
    tg = (p2 > bm) ? 2 : tg;     bm = fmaxf(p2, bm);
    tg = (p3 > bm) ? 3 : tg;
    float vt = (tg & 1) ? ((tg & 2) ? o.w : o.y) : ((tg & 2) ? o.z : o.x);
    float mx = fmaxf(fmaxf(o.x, o.y), fmaxf(o.z, o.w));
    float ss = __expf(o.x - mx) + __expf(o.y - mx) + __expf(o.z - mx) + __expf(o.w - mx);
    float v  = (mx - vt) + __logf(ss);
    *(float4*)(outs + (size_t)tid * 4) = make_float4(0.f, 0.f, 0.f, 0.f);
#pragma unroll
    for (int d = 1; d < 64; d <<= 1) v += __shfl_xor(v, d, 64);
    __shared__ float sm[16];
    int w = threadIdx.x >> 6;
    if ((threadIdx.x & 63) == 0) sm[w] = v;
    __syncthreads();
    if (threadIdx.x < 16) {
        float s = sm[threadIdx.x];
#pragma unroll
        for (int d = 1; d < 16; d <<= 1) s += __shfl_xor(s, d, 64);
        if (threadIdx.x == 0) atomicAdd(loss, s * (1.0f / NB));
    }
}

extern "C" void kernel_launch(void* const* d_in, const int* in_sizes, int n_in,
                              void* d_out, int out_size, void* d_ws, size_t ws_size,
                              hipStream_t stream) {
    (void)in_sizes; (void)n_in; (void)ws_size; (void)out_size;
    const float* gt   = (const float*)d_in[0];
    const float* eWih = (const float*)d_in[1];
    const float* eWhh = (const float*)d_in[2];
    const float* ebih = (const float*)d_in[3];
    const float* ebhh = (const float*)d_in[4];
    const float* dWih = (const float*)d_in[5];
    const float* dWhh = (const float*)d_in[6];
    const float* dbih = (const float*)d_in[7];
    const float* dbhh = (const float*)d_in[8];
    const float* oW   = (const float*)d_in[9];
    const float* ob   = (const float*)d_in[10];

    float* out  = (float*)d_out;       // out[0] = loss
    float* outs = out + 1;             // [NB][S_LEN][4] logit scratch == output_batch region
    float* hsc  = (float*)d_ws;        // [NB][NH] encoder->decoder hidden handoff (32 KiB)
    (void)hipMemsetAsync(d_out, 0, sizeof(float), stream);   // zero loss only
    enc_kernel<<<NB / 4, 64, 0, stream>>>(gt, eWih, eWhh, ebih, ebhh, hsc);
    dec_kernel<<<NB / 2, 64, 0, stream>>>(dWih, dWhh, dbih, dbhh, oW, ob, hsc, outs);
    loss_kernel<<<(NB * S_LEN) / 1024, 1024, 0, stream>>>(gt, outs, out);
}

// Round 3
// 3054.438 us; speedup vs baseline: 2.2654x; 1.0898x over previous
//
#include <hip/hip_runtime.h>

#define S_LEN 8192
#define NH 16
#define NV 4
#define NB 512

typedef _Float16 h2 __attribute__((ext_vector_type(2)));

#define L2E  1.4426950408889634f   // log2(e)
#define L2E2 2.8853900817779268f   // 2*log2(e)

// ---------- DPP helpers ----------
template<int R>
__device__ __forceinline__ float rotf(float v) {
    return __int_as_float(__builtin_amdgcn_mov_dpp(__float_as_int(v), 0x120 + R, 0xF, 0xF, true));
}
template<int R>
__device__ __forceinline__ h2 roth(h2 v) {    // row_ror:R on a packed half2 reg
    int i;
    __builtin_memcpy(&i, &v, 4);
    i = __builtin_amdgcn_mov_dpp(i, 0x120 + R, 0xF, 0xF, true);
    h2 o;
    __builtin_memcpy(&o, &i, 4);
    return o;
}
__device__ __forceinline__ float qxor1(float v) {  // quad_perm [1,0,3,2]
    return __int_as_float(__builtin_amdgcn_mov_dpp(__float_as_int(v), 0xB1, 0xF, 0xF, true));
}
__device__ __forceinline__ float qxor2(float v) {  // quad_perm [2,3,0,1]
    return __int_as_float(__builtin_amdgcn_mov_dpp(__float_as_int(v), 0x4E, 0xF, 0xF, true));
}

__device__ __forceinline__ float fex2(float x) { return __builtin_amdgcn_exp2f(x); }
__device__ __forceinline__ float frcp(float x) { return __builtin_amdgcn_rcpf(x); }
// pre-scaled sigmoid: x already multiplied by log2(e) (folded into weights)
__device__ __forceinline__ float fsig2(float x) { return frcp(1.0f + fex2(-x)); }
__device__ __forceinline__ float4 ld4(const float* p) { return *(const float4*)p; }

// Pack two f32 to half2 via v_cvt_pkrtz_f16_f32.
__device__ __forceinline__ h2 pkh(float a, float b) {
    auto t = __builtin_amdgcn_cvt_pkrtz(a, b);
    h2 o;
    __builtin_memcpy(&o, &t, 4);
    return o;
}

// Broadcast-exchange between wave halves (verified semantics: vdst[32+i] <-> vsrc[i]).
// After call: lo = value computed by lanes 0-31 (column-matched), hi = value from lanes 32-63.
__device__ __forceinline__ void bcast32(float v, float& lo, float& hi) {
    lo = v; hi = v;
    asm("v_permlane32_swap_b32 %0, %1" : "+v"(lo), "+v"(hi));
}

// hp[k] = packed (h[(j+sgn*2k)&15], h[(j+sgn*(2k+1))&15]) as half2.
#define FILL_HP16(hp, h)                                      \
    do {                                                      \
        h2 p0_ = pkh((h), rotf<1>(h));                        \
        hp[0] = p0_;                                          \
        hp[1] = roth<2>(p0_);                                 \
        hp[2] = roth<4>(p0_);                                 \
        hp[3] = roth<6>(p0_);                                 \
        hp[4] = roth<8>(p0_);                                 \
        hp[5] = roth<10>(p0_);                                \
        hp[6] = roth<12>(p0_);                                \
        hp[7] = roth<14>(p0_);                                \
    } while (0)

// 16-dot: 8 dot2 + 1 add, two chains of depth 4.
__device__ __forceinline__ float dotd2(const h2* __restrict__ w, const h2* hp, float start) {
    float a = __builtin_amdgcn_fdot2(w[0], hp[0], start, false);
    float b = __builtin_amdgcn_fdot2(w[1], hp[1], 0.0f, false);
    a = __builtin_amdgcn_fdot2(w[2], hp[2], a, false);
    b = __builtin_amdgcn_fdot2(w[3], hp[3], b, false);
    a = __builtin_amdgcn_fdot2(w[4], hp[4], a, false);
    b = __builtin_amdgcn_fdot2(w[5], hp[5], b, false);
    a = __builtin_amdgcn_fdot2(w[6], hp[6], a, false);
    b = __builtin_amdgcn_fdot2(w[7], hp[7], b, false);
    return a + b;
}
// 20-dot (16 h + 4 x): 10 dot2 + 1 add, two chains of depth 5.
__device__ __forceinline__ float dotd2x(const h2* __restrict__ w, const h2* hp, float start) {
    float a = __builtin_amdgcn_fdot2(w[0], hp[0], start, false);
    float b = __builtin_amdgcn_fdot2(w[1], hp[1], 0.0f, false);
    a = __builtin_amdgcn_fdot2(w[2], hp[2], a, false);
    b = __builtin_amdgcn_fdot2(w[3], hp[3], b, false);
    a = __builtin_amdgcn_fdot2(w[4], hp[4], a, false);
    b = __builtin_amdgcn_fdot2(w[5], hp[5], b, false);
    a = __builtin_amdgcn_fdot2(w[6], hp[6], a, false);
    b = __builtin_amdgcn_fdot2(w[7], hp[7], b, false);
    a = __builtin_amdgcn_fdot2(w[8], hp[8], a, false);
    b = __builtin_amdgcn_fdot2(w[9], hp[9], b, false);
    return a + b;
}

// ======================= ENCODER =======================
// 256 blocks x 64 threads; 2 elements/wave, role-split across wave halves.
// roleA (lanes 0-31, rows 0,1): dotA = full r pre-act (h + x via k16-19), dotB = hn.
// roleB (lanes 32-63, rows 2,3): dotA = full z pre-act,                  dotB = inn (x-only).
// Role exchange via one v_permlane32_swap_b32 per dot (partner rows = same element).
// r/z weights+biases pre-scaled by log2(e); n-gate (hn, inn) by 2*log2(e):
// sigmoid = rcp(1+exp2(-x')), tanh branch w2 = rcp(1+exp2(-y')) = sigma(2y).
__global__ __launch_bounds__(64, 1) void enc_kernel(
    const float* __restrict__ gt,
    const float* __restrict__ eWih, const float* __restrict__ eWhh,
    const float* __restrict__ ebih, const float* __restrict__ ebhh,
    float* __restrict__ hsc)
{
    const int lane = threadIdx.x;
    const int j    = lane & 15;
    const int row  = lane >> 4;
    const bool isLo = (lane < 32);
    const int b    = blockIdx.x * 2 + (row & 1);

    int probe = __builtin_amdgcn_mov_dpp(j, 0x121, 0xF, 0xF, true);
    const int sgn = (probe == ((j + 1) & 15)) ? 1 : -1;

    const float* gb = gt + (size_t)b * (NV * S_LEN);

    const int gA = isLo ? 0 : 1;      // roleA: r rows; roleB: z rows
    h2 wA[10], wB[10];
#pragma unroll
    for (int p = 0; p < 8; ++p) {
        int k0 = (j + sgn * (2 * p)) & 15;
        int k1 = (j + sgn * (2 * p + 1)) & 15;
        wA[p] = (h2){(_Float16)(L2E * eWhh[(gA * NH + j) * NH + k0]),
                     (_Float16)(L2E * eWhh[(gA * NH + j) * NH + k1])};
        float n0 = isLo ? (L2E2 * eWhh[(2 * NH + j) * NH + k0]) : 0.0f;
        float n1 = isLo ? (L2E2 * eWhh[(2 * NH + j) * NH + k1]) : 0.0f;
        wB[p] = (h2){(_Float16)n0, (_Float16)n1};
    }
#pragma unroll
    for (int p = 0; p < 2; ++p) {     // x-part, k16-19
        wA[8 + p] = (h2){(_Float16)(L2E * eWih[(gA * NH + j) * NV + 2 * p]),
                         (_Float16)(L2E * eWih[(gA * NH + j) * NV + 2 * p + 1])};
        float n0 = isLo ? 0.0f : (L2E2 * eWih[(2 * NH + j) * NV + 2 * p]);
        float n1 = isLo ? 0.0f : (L2E2 * eWih[(2 * NH + j) * NV + 2 * p + 1]);
        wB[8 + p] = (h2){(_Float16)n0, (_Float16)n1};
    }
    const float startA = L2E * (ebih[gA * NH + j] + ebhh[gA * NH + j]);
    const float startB = isLo ? (L2E2 * ebhh[2 * NH + j]) : (L2E2 * ebih[2 * NH + j]);

    float h = 0.0f;

    auto estep = [&](float x0, float x1, float x2, float x3) {
        h2 hp[10];
        FILL_HP16(hp, h);
        hp[8] = pkh(x0, x1);
        hp[9] = pkh(x2, x3);
        float vA = dotd2x(wA, hp, startA);     // roleA: ar' | roleB: az'
        float vB = dotd2x(wB, hp, startB);     // roleA: hn' | roleB: inn'
        float ar, az, hn, inn;
        bcast32(vA, ar, az);
        bcast32(vB, hn, inn);
        float r  = fsig2(ar);
        float z  = fsig2(az);
        float y  = fmaf(r, hn, inn);           // = 2*log2(e) * (inn + r*hn)
        float w2 = fsig2(y);                   // = sigma(2y)
        float t2 = fmaf(-2.0f, z, 2.0f);
        float tb = fmaf(z, h, z - 1.0f);
        h = fmaf(w2, t2, tb);
    };

    {
        float4 A0 = ld4(gb + 0 * S_LEN), A1 = ld4(gb + 1 * S_LEN),
               A2 = ld4(gb + 2 * S_LEN), A3 = ld4(gb + 3 * S_LEN);
        float4 B0 = ld4(gb + 0 * S_LEN + 4), B1 = ld4(gb + 1 * S_LEN + 4),
               B2 = ld4(gb + 2 * S_LEN + 4), B3 = ld4(gb + 3 * S_LEN + 4);
        for (int t = 0; t < S_LEN; t += 8) {
            estep(A0.x, A1.x, A2.x, A3.x);
            estep(A0.y, A1.y, A2.y, A3.y);
            estep(A0.z, A1.z, A2.z, A3.z);
            estep(A0.w, A1.w, A2.w, A3.w);
            int ta = t + 8;  if (ta > S_LEN - 4) ta = S_LEN - 4;
            A0 = ld4(gb + 0 * S_LEN + ta); A1 = ld4(gb + 1 * S_LEN + ta);
            A2 = ld4(gb + 2 * S_LEN + ta); A3 = ld4(gb + 3 * S_LEN + ta);
            estep(B0.x, B1.x, B2.x, B3.x);
            estep(B0.y, B1.y, B2.y, B3.y);
            estep(B0.z, B1.z, B2.z, B3.z);
            estep(B0.w, B1.w, B2.w, B3.w);
            int tb2 = t + 12; if (tb2 > S_LEN - 4) tb2 = S_LEN - 4;
            B0 = ld4(gb + 0 * S_LEN + tb2); B1 = ld4(gb + 1 * S_LEN + tb2);
            B2 = ld4(gb + 2 * S_LEN + tb2); B3 = ld4(gb + 3 * S_LEN + tb2);
        }
    }

    if (isLo) hsc[(size_t)b * NH + j] = h;   // rows 0,1 cover both elements
}

// ======================= DECODER =======================
// 256 blocks x 64 threads; 2 elements/wave, role-split (round-2 verified structure).
// lo rows: r-gate + n-gate dots; hi rows: z-gate + out dots.
// Improvements vs round-2: exchange via bcast32 (no cndmask), exp2-prescaled gates.
__global__ __launch_bounds__(64, 1) void dec_kernel(
    const float* __restrict__ dWih, const float* __restrict__ dWhh,
    const float* __restrict__ dbih, const float* __restrict__ dbhh,
    const float* __restrict__ oW,  const float* __restrict__ ob,
    const float* __restrict__ hsc,
    float* __restrict__ outs)                 // [NB][S_LEN][4] logit scratch
{
    const int lane = threadIdx.x;
    const int j    = lane & 15;
    const int q    = j & 3;
    const int row  = lane >> 4;
    const bool isLo = (lane < 32);
    const int b    = blockIdx.x * 2 + (row & 1);

    int probe = __builtin_amdgcn_mov_dpp(j, 0x121, 0xF, 0xF, true);
    const int sgn = (probe == ((j + 1) & 15)) ? 1 : -1;

    // wA: lo -> r rows (x L2E), hi -> z rows (x L2E).
    // wB: lo -> n rows (x L2E2), hi -> oW rows (UNSCALED; logits must be exact).
    const int gA = isLo ? 0 : 1;
    h2 wA[8], wB[8];
#pragma unroll
    for (int p = 0; p < 8; ++p) {
        int k0 = (j + sgn * (2 * p)) & 15;
        int k1 = (j + sgn * (2 * p + 1)) & 15;
        wA[p] = (h2){(_Float16)(L2E * dWhh[(gA * NH + j) * NH + k0]),
                     (_Float16)(L2E * dWhh[(gA * NH + j) * NH + k1])};
        float w0 = isLo ? (L2E2 * dWhh[(2 * NH + j) * NH + k0]) : oW[q * NH + k0];
        float w1 = isLo ? (L2E2 * dWhh[(2 * NH + j) * NH + k1]) : oW[q * NH + k1];
        wB[p] = (h2){(_Float16)w0, (_Float16)w1};
    }
    const float bNi  = dbih[2 * NH + j];
    const float bNiS = L2E2 * bNi;
    const float biasA  = L2E * (dbih[gA * NH + j] + dbhh[gA * NH + j]);
    const float startB = isLo ? (L2E2 * dbhh[2 * NH + j]) : ob[q];
    // per-class one-hot x-terms, REGISTER order m (class = m ^ q), pre-scaled:
    float SA[NV], KN[NV];
#pragma unroll
    for (int m = 0; m < NV; ++m) {
        int c = m ^ q;
        SA[m] = L2E * dWih[(gA * NH + j) * NV + c];
        KN[m] = L2E2 * (bNi + dWih[(2 * NH + j) * NV + c]);
    }

    float h = hsc[(size_t)b * NH + j];

    int oidx = (b << 15) + q;                 // (b*S_LEN + 0)*4 + q
    const bool storer = isLo && (j < 4);

    auto dstep = [&]() {
        h2 hp[8];
        FILL_HP16(hp, h);
        float aA = dotd2(wA, hp, biasA);      // lo: ar' (pre-K) | hi: az' (pre-K)
        float vB = dotd2(wB, hp, startB);     // lo: hn'         | hi: oa
        float hn, oa;
        bcast32(vB, hn, oa);
        if (storer) outs[oidx] = oa;          // logits of step t-1
        oidx += 4;
        // argmax over the quad (identical comparisons to round-0)
        float ob_ = qxor1(oa);                // out[q^1]
        float oc_ = qxor2(oa);                // out[q^2]
        float od_ = qxor2(ob_);               // out[q^3]
        bool cA = ob_ > oa;  float mA = fmaxf(oa, ob_);
        bool cB = od_ > oc_; float mB = fmaxf(oc_, od_);
        bool hi_ = mB > mA;
        float KA  = hi_ ? (cB ? SA[3] : SA[2]) : (cA ? SA[1] : SA[0]);
        float KN_ = hi_ ? (cB ? KN[3] : KN[2]) : (cA ? KN[1] : KN[0]);
        float sg  = fsig2(aA + KA);           // lo: r | hi: z
        float r, z;
        bcast32(sg, r, z);
        float y   = fmaf(r, hn, KN_);
        float w2  = fsig2(y);
        float t2  = fmaf(-2.0f, z, 2.0f);
        float tb  = fmaf(z, h, z - 1.0f);
        h = fmaf(w2, t2, tb);
    };

    // t = 0: x0 = zeros — no K terms, no store, no argmax
    {
        h2 hp[8];
        FILL_HP16(hp, h);
        float aA = dotd2(wA, hp, biasA);
        float vB = dotd2(wB, hp, startB);
        float hn, oa;
        bcast32(vB, hn, oa);
        float sg = fsig2(aA);
        float r, z;
        bcast32(sg, r, z);
        float y  = fmaf(r, hn, bNiS);
        float w2 = fsig2(y);
        float t2 = fmaf(-2.0f, z, 2.0f);
        float tb = fmaf(z, h, z - 1.0f);
        h = fmaf(w2, t2, tb);
    }
    for (int u = 0; u < S_LEN - 4; u += 4) {  // t = 1..8188
        dstep(); dstep(); dstep(); dstep();
    }
    dstep(); dstep(); dstep();                // t = 8189..8191

    // tail: logits of final step (t = S-1)
    {
        h2 hp[8];
        FILL_HP16(hp, h);
        float vB = dotd2(wB, hp, startB);
        float hn, oa;
        bcast32(vB, hn, oa);
        if (storer) outs[oidx] = oa;
    }
}

// Epilogue: NLL over all (b,t) from stored logits + gt targets; zero the scratch.
__global__ __launch_bounds__(1024) void loss_kernel(
    const float* __restrict__ gt, float* __restrict__ outs, float* __restrict__ loss)
{
    int tid = blockIdx.x * 1024 + threadIdx.x;   // over NB*S_LEN
    int t = tid & (S_LEN - 1);
    int b = tid >> 13;
    float4 o = *(const float4*)(outs + (size_t)tid * 4);
    const float* g = gt + (size_t)b * (NV * S_LEN) + t;
    float p0 = g[0], p1 = g[S_LEN], p2 = g[2 * S_LEN], p3 = g[3 * S_LEN];
    int tg = (p1 > p0) ? 1 : 0;  float bm = fmaxf(p0, p1);
    tg = (p2 > bm) ? 2 : tg;     bm = fmaxf(p2, bm);
    tg = (p3 > bm) ? 3 : tg;
    float vt = (tg & 1) ? ((tg & 2) ? o.w : o.y) : ((tg & 2) ? o.z : o.x);
    float mx = fmaxf(fmaxf(o.x, o.y), fmaxf(o.z, o.w));
    float ss = __expf(o.x - mx) + __expf(o.y - mx) + __expf(o.z - mx) + __expf(o.w - mx);
    float v  = (mx - vt) + __logf(ss);
    *(float4*)(outs + (size_t)tid * 4) = make_float4(0.f, 0.f, 0.f, 0.f);
#pragma unroll
    for (int d = 1; d < 64; d <<= 1) v += __shfl_xor(v, d, 64);
    __shared__ float sm[16];
    int w = threadIdx.x >> 6;
    if ((threadIdx.x & 63) == 0) sm[w] = v;
    __syncthreads();
    if (threadIdx.x < 16) {
        float s = sm[threadIdx.x];
#pragma unroll
        for (int d = 1; d < 16; d <<= 1) s += __shfl_xor(s, d, 64);
        if (threadIdx.x == 0) atomicAdd(loss, s * (1.0f / NB));
    }
}

extern "C" void kernel_launch(void* const* d_in, const int* in_sizes, int n_in,
                              void* d_out, int out_size, void* d_ws, size_t ws_size,
                              hipStream_t stream) {
    (void)in_sizes; (void)n_in; (void)ws_size; (void)out_size;
    const float* gt   = (const float*)d_in[0];
    const float* eWih = (const float*)d_in[1];
    const float* eWhh = (const float*)d_in[2];
    const float* ebih = (const float*)d_in[3];
    const float* ebhh = (const float*)d_in[4];
    const float* dWih = (const float*)d_in[5];
    const float* dWhh = (const float*)d_in[6];
    const float* dbih = (const float*)d_in[7];
    const float* dbhh = (const float*)d_in[8];
    const float* oW   = (const float*)d_in[9];
    const float* ob   = (const float*)d_in[10];

    float* out  = (float*)d_out;       // out[0] = loss
    float* outs = out + 1;             // [NB][S_LEN][4] logit scratch == output_batch region
    float* hsc  = (float*)d_ws;        // [NB][NH] encoder->decoder hidden handoff
    (void)hipMemsetAsync(d_out, 0, sizeof(float), stream);   // zero loss only
    enc_kernel<<<NB / 2, 64, 0, stream>>>(gt, eWih, eWhh, ebih, ebhh, hsc);
    dec_kernel<<<NB / 2, 64, 0, stream>>>(dWih, dWhh, dbih, dbhh, oW, ob, hsc, outs);
    loss_kernel<<<(NB * S_LEN) / 1024, 1024, 0, stream>>>(gt, outs, out);
}

// Round 4
// 2986.504 us; speedup vs baseline: 2.3169x; 1.0227x over previous
//
#include <hip/hip_runtime.h>

#define S_LEN 8192
#define NH 16
#define NV 4
#define NB 512

typedef _Float16 h2 __attribute__((ext_vector_type(2)));

#define L2E  1.4426950408889634f   // log2(e)
#define L2E2 2.8853900817779268f   // 2*log2(e)

// ---------- DPP helpers ----------
template<int R>
__device__ __forceinline__ float rotf(float v) {
    return __int_as_float(__builtin_amdgcn_mov_dpp(__float_as_int(v), 0x120 + R, 0xF, 0xF, true));
}
template<int R>
__device__ __forceinline__ h2 roth(h2 v) {    // row_ror:R on a packed half2 reg
    int i;
    __builtin_memcpy(&i, &v, 4);
    i = __builtin_amdgcn_mov_dpp(i, 0x120 + R, 0xF, 0xF, true);
    h2 o;
    __builtin_memcpy(&o, &i, 4);
    return o;
}
__device__ __forceinline__ float qxor1(float v) {  // quad_perm [1,0,3,2]
    return __int_as_float(__builtin_amdgcn_mov_dpp(__float_as_int(v), 0xB1, 0xF, 0xF, true));
}
__device__ __forceinline__ float qxor2(float v) {  // quad_perm [2,3,0,1]
    return __int_as_float(__builtin_amdgcn_mov_dpp(__float_as_int(v), 0x4E, 0xF, 0xF, true));
}
__device__ __forceinline__ float qxor3(float v) {  // quad_perm [3,2,1,0]
    return __int_as_float(__builtin_amdgcn_mov_dpp(__float_as_int(v), 0x1B, 0xF, 0xF, true));
}

__device__ __forceinline__ float fex2(float x) { return __builtin_amdgcn_exp2f(x); }
__device__ __forceinline__ float frcp(float x) { return __builtin_amdgcn_rcpf(x); }
// pre-scaled sigmoid: x already multiplied by log2(e) (folded into weights)
__device__ __forceinline__ float fsig2(float x) { return frcp(1.0f + fex2(-x)); }
__device__ __forceinline__ float4 ld4(const float* p) { return *(const float4*)p; }

// Pack two f32 to half2 via v_cvt_pkrtz_f16_f32.
__device__ __forceinline__ h2 pkh(float a, float b) {
    auto t = __builtin_amdgcn_cvt_pkrtz(a, b);
    h2 o;
    __builtin_memcpy(&o, &t, 4);
    return o;
}

// Broadcast-exchange between wave halves: 1 mov + 1 v_permlane32_swap_b32.
// swap(a,b): a = {a.lo, b.lo}, b = {a.hi, b.hi}. With a = copy(v), b = v:
// a = {v.lo, v.lo} (lo-half's value everywhere), b = {v.hi, v.hi}.
__device__ __forceinline__ void bcast32(float v, float& lo, float& hi) {
    lo = v;
    asm("v_permlane32_swap_b32 %0, %1" : "+v"(lo), "+v"(v));
    hi = v;
}

// hp[k] = packed (h[(j+sgn*2k)&15], h[(j+sgn*(2k+1))&15]) as half2.
#define FILL_HP16(hp, h)                                      \
    do {                                                      \
        h2 p0_ = pkh((h), rotf<1>(h));                        \
        hp[0] = p0_;                                          \
        hp[1] = roth<2>(p0_);                                 \
        hp[2] = roth<4>(p0_);                                 \
        hp[3] = roth<6>(p0_);                                 \
        hp[4] = roth<8>(p0_);                                 \
        hp[5] = roth<10>(p0_);                                \
        hp[6] = roth<12>(p0_);                                \
        hp[7] = roth<14>(p0_);                                \
    } while (0)

// 16-dot: 8 dot2 + 1 add, two chains of depth 4.
__device__ __forceinline__ float dotd2(const h2* __restrict__ w, const h2* hp, float start) {
    float a = __builtin_amdgcn_fdot2(w[0], hp[0], start, false);
    float b = __builtin_amdgcn_fdot2(w[1], hp[1], 0.0f, false);
    a = __builtin_amdgcn_fdot2(w[2], hp[2], a, false);
    b = __builtin_amdgcn_fdot2(w[3], hp[3], b, false);
    a = __builtin_amdgcn_fdot2(w[4], hp[4], a, false);
    b = __builtin_amdgcn_fdot2(w[5], hp[5], b, false);
    a = __builtin_amdgcn_fdot2(w[6], hp[6], a, false);
    b = __builtin_amdgcn_fdot2(w[7], hp[7], b, false);
    return a + b;
}
// 20-dot (16 h + 4 x): 10 dot2 + 1 add, two chains of depth 5.
__device__ __forceinline__ float dotd2x(const h2* __restrict__ w, const h2* hp, float start) {
    float a = __builtin_amdgcn_fdot2(w[0], hp[0], start, false);
    float b = __builtin_amdgcn_fdot2(w[1], hp[1], 0.0f, false);
    a = __builtin_amdgcn_fdot2(w[2], hp[2], a, false);
    b = __builtin_amdgcn_fdot2(w[3], hp[3], b, false);
    a = __builtin_amdgcn_fdot2(w[4], hp[4], a, false);
    b = __builtin_amdgcn_fdot2(w[5], hp[5], b, false);
    a = __builtin_amdgcn_fdot2(w[6], hp[6], a, false);
    b = __builtin_amdgcn_fdot2(w[7], hp[7], b, false);
    a = __builtin_amdgcn_fdot2(w[8], hp[8], a, false);
    b = __builtin_amdgcn_fdot2(w[9], hp[9], b, false);
    return a + b;
}

// ======================= FUSED ENC+DEC =======================
// 256 blocks x 64 threads; 2 elements/wave, role-split across wave halves.
// Element mapping is identical in both phases (rows {0,2}=b0, {1,3}=b1),
// so the encoder's final h hands off to the decoder IN REGISTER (no hsc).
//
// Encoder roles: lo = full r pre-act (h + x via k16-19) & hn; hi = full z
// pre-act & inn. Decoder roles: lo = r-gate & n-gate dots; hi = z-gate &
// out dots. Exchange via v_permlane32_swap_b32.
// r/z weights+biases pre-scaled by log2(e); n-gate by 2*log2(e); oW exact.
__global__ __launch_bounds__(64, 1) void rnn_kernel(
    const float* __restrict__ gt,
    const float* __restrict__ eWih, const float* __restrict__ eWhh,
    const float* __restrict__ ebih, const float* __restrict__ ebhh,
    const float* __restrict__ dWih, const float* __restrict__ dWhh,
    const float* __restrict__ dbih, const float* __restrict__ dbhh,
    const float* __restrict__ oW,  const float* __restrict__ ob,
    float* __restrict__ outs)                 // [NB][S_LEN][4] logit scratch
{
    const int lane = threadIdx.x;
    const int j    = lane & 15;
    const int q    = j & 3;
    const int row  = lane >> 4;
    const bool isLo = (lane < 32);
    const int b    = blockIdx.x * 2 + (row & 1);

    int probe = __builtin_amdgcn_mov_dpp(j, 0x121, 0xF, 0xF, true);
    const int sgn = (probe == ((j + 1) & 15)) ? 1 : -1;

    float h = 0.0f;

    // ---------------- encoder phase ----------------
    {
        const float* gb = gt + (size_t)b * (NV * S_LEN);
        const int gA = isLo ? 0 : 1;      // roleA: r rows; roleB: z rows
        h2 wA[10], wB[10];
#pragma unroll
        for (int p = 0; p < 8; ++p) {
            int k0 = (j + sgn * (2 * p)) & 15;
            int k1 = (j + sgn * (2 * p + 1)) & 15;
            wA[p] = (h2){(_Float16)(L2E * eWhh[(gA * NH + j) * NH + k0]),
                         (_Float16)(L2E * eWhh[(gA * NH + j) * NH + k1])};
            float n0 = isLo ? (L2E2 * eWhh[(2 * NH + j) * NH + k0]) : 0.0f;
            float n1 = isLo ? (L2E2 * eWhh[(2 * NH + j) * NH + k1]) : 0.0f;
            wB[p] = (h2){(_Float16)n0, (_Float16)n1};
        }
#pragma unroll
        for (int p = 0; p < 2; ++p) {     // x-part, k16-19
            wA[8 + p] = (h2){(_Float16)(L2E * eWih[(gA * NH + j) * NV + 2 * p]),
                             (_Float16)(L2E * eWih[(gA * NH + j) * NV + 2 * p + 1])};
            float n0 = isLo ? 0.0f : (L2E2 * eWih[(2 * NH + j) * NV + 2 * p]);
            float n1 = isLo ? 0.0f : (L2E2 * eWih[(2 * NH + j) * NV + 2 * p + 1]);
            wB[8 + p] = (h2){(_Float16)n0, (_Float16)n1};
        }
        const float startA = L2E * (ebih[gA * NH + j] + ebhh[gA * NH + j]);
        const float startB = isLo ? (L2E2 * ebhh[2 * NH + j]) : (L2E2 * ebih[2 * NH + j]);

        auto estep = [&](float x0, float x1, float x2, float x3) {
            h2 hp[10];
            FILL_HP16(hp, h);
            hp[8] = pkh(x0, x1);
            hp[9] = pkh(x2, x3);
            float vA = dotd2x(wA, hp, startA);     // roleA: ar' | roleB: az'
            float vB = dotd2x(wB, hp, startB);     // roleA: hn' | roleB: inn'
            float ar, az, hn, inn;
            bcast32(vA, ar, az);
            bcast32(vB, hn, inn);
            float r  = fsig2(ar);
            float z  = fsig2(az);
            float y  = fmaf(r, hn, inn);           // = 2*log2(e) * (inn + r*hn)
            float w2 = fsig2(y);                   // = sigma(2y)
            float t2 = fmaf(-2.0f, z, 2.0f);
            float tb = fmaf(z, h, z - 1.0f);
            h = fmaf(w2, t2, tb);
        };

        float4 A0 = ld4(gb + 0 * S_LEN), A1 = ld4(gb + 1 * S_LEN),
               A2 = ld4(gb + 2 * S_LEN), A3 = ld4(gb + 3 * S_LEN);
        float4 B0 = ld4(gb + 0 * S_LEN + 4), B1 = ld4(gb + 1 * S_LEN + 4),
               B2 = ld4(gb + 2 * S_LEN + 4), B3 = ld4(gb + 3 * S_LEN + 4);
        for (int t = 0; t < S_LEN; t += 8) {
            estep(A0.x, A1.x, A2.x, A3.x);
            estep(A0.y, A1.y, A2.y, A3.y);
            estep(A0.z, A1.z, A2.z, A3.z);
            estep(A0.w, A1.w, A2.w, A3.w);
            int ta = t + 8;  if (ta > S_LEN - 4) ta = S_LEN - 4;
            A0 = ld4(gb + 0 * S_LEN + ta); A1 = ld4(gb + 1 * S_LEN + ta);
            A2 = ld4(gb + 2 * S_LEN + ta); A3 = ld4(gb + 3 * S_LEN + ta);
            estep(B0.x, B1.x, B2.x, B3.x);
            estep(B0.y, B1.y, B2.y, B3.y);
            estep(B0.z, B1.z, B2.z, B3.z);
            estep(B0.w, B1.w, B2.w, B3.w);
            int tb2 = t + 12; if (tb2 > S_LEN - 4) tb2 = S_LEN - 4;
            B0 = ld4(gb + 0 * S_LEN + tb2); B1 = ld4(gb + 1 * S_LEN + tb2);
            B2 = ld4(gb + 2 * S_LEN + tb2); B3 = ld4(gb + 3 * S_LEN + tb2);
        }
    }

    // ---------------- decoder phase ----------------
    // wA: lo -> r rows (x L2E), hi -> z rows (x L2E).
    // wB: lo -> n rows (x L2E2), hi -> oW rows (UNSCALED; logits must be exact).
    const int gA = isLo ? 0 : 1;
    h2 wA[8], wB[8];
#pragma unroll
    for (int p = 0; p < 8; ++p) {
        int k0 = (j + sgn * (2 * p)) & 15;
        int k1 = (j + sgn * (2 * p + 1)) & 15;
        wA[p] = (h2){(_Float16)(L2E * dWhh[(gA * NH + j) * NH + k0]),
                     (_Float16)(L2E * dWhh[(gA * NH + j) * NH + k1])};
        float w0 = isLo ? (L2E2 * dWhh[(2 * NH + j) * NH + k0]) : oW[q * NH + k0];
        float w1 = isLo ? (L2E2 * dWhh[(2 * NH + j) * NH + k1]) : oW[q * NH + k1];
        wB[p] = (h2){(_Float16)w0, (_Float16)w1};
    }
    const float bNi  = dbih[2 * NH + j];
    const float bNiS = L2E2 * bNi;
    const float biasA  = L2E * (dbih[gA * NH + j] + dbhh[gA * NH + j]);
    const float startB = isLo ? (L2E2 * dbhh[2 * NH + j]) : ob[q];
    // per-class one-hot x-terms, REGISTER order m (class = m ^ q), pre-scaled:
    float SA[NV], KN[NV];
#pragma unroll
    for (int m = 0; m < NV; ++m) {
        int c = m ^ q;
        SA[m] = L2E * dWih[(gA * NH + j) * NV + c];
        KN[m] = L2E2 * (bNi + dWih[(2 * NH + j) * NV + c]);
    }

    int oidx = (b << 15) + q;                 // (b*S_LEN + 0)*4 + q
    const bool storer = isLo && (j < 4);

    // koff is a compile-time literal under #pragma unroll: the store address
    // folds into the global_store immediate offset (one oidx add per 8 steps).
    auto dstep = [&](int koff) {
        h2 hp[8];
        FILL_HP16(hp, h);
        float aA = dotd2(wA, hp, biasA);      // lo: ar' (pre-K) | hi: az' (pre-K)
        float vB = dotd2(wB, hp, startB);     // lo: hn'         | hi: oa
        float hn, oa;
        bcast32(vB, hn, oa);
        if (storer) outs[oidx + koff] = oa;   // logits of step t-1
        // argmax over the quad: 3 INDEPENDENT DPP fetches (depth 1)
        float ob_ = qxor1(oa);                // out[q^1]
        float oc_ = qxor2(oa);                // out[q^2]
        float od_ = qxor3(oa);                // out[q^3]
        bool cA = ob_ > oa;  float mA = fmaxf(oa, ob_);
        bool cB = od_ > oc_; float mB = fmaxf(oc_, od_);
        bool hi_ = mB > mA;
        float KA  = hi_ ? (cB ? SA[3] : SA[2]) : (cA ? SA[1] : SA[0]);
        float KN_ = hi_ ? (cB ? KN[3] : KN[2]) : (cA ? KN[1] : KN[0]);
        float sg  = fsig2(aA + KA);           // lo: r | hi: z
        float r, z;
        bcast32(sg, r, z);
        float y   = fmaf(r, hn, KN_);
        float w2  = fsig2(y);
        float t2  = fmaf(-2.0f, z, 2.0f);
        float tb  = fmaf(z, h, z - 1.0f);
        h = fmaf(w2, t2, tb);
    };

    // t = 0: x0 = zeros — no K terms, no store, no argmax
    {
        h2 hp[8];
        FILL_HP16(hp, h);
        float aA = dotd2(wA, hp, biasA);
        float vB = dotd2(wB, hp, startB);
        float hn, oa;
        bcast32(vB, hn, oa);
        float sg = fsig2(aA);
        float r, z;
        bcast32(sg, r, z);
        float y  = fmaf(r, hn, bNiS);
        float w2 = fsig2(y);
        float t2 = fmaf(-2.0f, z, 2.0f);
        float tb = fmaf(z, h, z - 1.0f);
        h = fmaf(w2, t2, tb);
    }
    // t = 1..8191: 8191 dsteps = 1023 x 8 + 7
    for (int u = 0; u < 8184; u += 8) {
#pragma unroll
        for (int k = 0; k < 8; ++k) dstep(k * 4);
        oidx += 32;
    }
#pragma unroll
    for (int k = 0; k < 7; ++k) dstep(k * 4);
    oidx += 28;

    // tail: logits of final step (t = S-1)
    {
        h2 hp[8];
        FILL_HP16(hp, h);
        float vB = dotd2(wB, hp, startB);
        float hn, oa;
        bcast32(vB, hn, oa);
        if (storer) outs[oidx] = oa;
    }
}

// Epilogue: NLL over all (b,t) from stored logits + gt targets; zero the scratch.
__global__ __launch_bounds__(1024) void loss_kernel(
    const float* __restrict__ gt, float* __restrict__ outs, float* __restrict__ loss)
{
    int tid = blockIdx.x * 1024 + threadIdx.x;   // over NB*S_LEN
    int t = tid & (S_LEN - 1);
    int b = tid >> 13;
    float4 o = *(const float4*)(outs + (size_t)tid * 4);
    const float* g = gt + (size_t)b * (NV * S_LEN) + t;
    float p0 = g[0], p1 = g[S_LEN], p2 = g[2 * S_LEN], p3 = g[3 * S_LEN];
    int tg = (p1 > p0) ? 1 : 0;  float bm = fmaxf(p0, p1);
    tg = (p2 > bm) ? 2 : tg;     bm = fmaxf(p2, bm);
    tg = (p3 > bm) ? 3 : tg;
    float vt = (tg & 1) ? ((tg & 2) ? o.w : o.y) : ((tg & 2) ? o.z : o.x);
    float mx = fmaxf(fmaxf(o.x, o.y), fmaxf(o.z, o.w));
    float ss = __expf(o.x - mx) + __expf(o.y - mx) + __expf(o.z - mx) + __expf(o.w - mx);
    float v  = (mx - vt) + __logf(ss);
    *(float4*)(outs + (size_t)tid * 4) = make_float4(0.f, 0.f, 0.f, 0.f);
#pragma unroll
    for (int d = 1; d < 64; d <<= 1) v += __shfl_xor(v, d, 64);
    __shared__ float sm[16];
    int w = threadIdx.x >> 6;
    if ((threadIdx.x & 63) == 0) sm[w] = v;
    __syncthreads();
    if (threadIdx.x < 16) {
        float s = sm[threadIdx.x];
#pragma unroll
        for (int d = 1; d < 16; d <<= 1) s += __shfl_xor(s, d, 64);
        if (threadIdx.x == 0) atomicAdd(loss, s * (1.0f / NB));
    }
}

extern "C" void kernel_launch(void* const* d_in, const int* in_sizes, int n_in,
                              void* d_out, int out_size, void* d_ws, size_t ws_size,
                              hipStream_t stream) {
    (void)in_sizes; (void)n_in; (void)d_ws; (void)ws_size; (void)out_size;
    const float* gt   = (const float*)d_in[0];
    const float* eWih = (const float*)d_in[1];
    const float* eWhh = (const float*)d_in[2];
    const float* ebih = (const float*)d_in[3];
    const float* ebhh = (const float*)d_in[4];
    const float* dWih = (const float*)d_in[5];
    const float* dWhh = (const float*)d_in[6];
    const float* dbih = (const float*)d_in[7];
    const float* dbhh = (const float*)d_in[8];
    const float* oW   = (const float*)d_in[9];
    const float* ob   = (const float*)d_in[10];

    float* out  = (float*)d_out;       // out[0] = loss
    float* outs = out + 1;             // [NB][S_LEN][4] logit scratch == output_batch region
    (void)hipMemsetAsync(d_out, 0, sizeof(float), stream);   // zero loss only
    rnn_kernel<<<NB / 2, 64, 0, stream>>>(gt, eWih, eWhh, ebih, ebhh,
                                          dWih, dWhh, dbih, dbhh, oW, ob, outs);
    loss_kernel<<<(NB * S_LEN) / 1024, 1024, 0, stream>>>(gt, outs, out);
}

// Round 5
// 2857.082 us; speedup vs baseline: 2.4219x; 1.0453x over previous
//
#include <hip/hip_runtime.h>

#define S_LEN 8192
#define NH 16
#define NV 4
#define NB 512

typedef _Float16 h2 __attribute__((ext_vector_type(2)));

#define L2E  1.4426950408889634f   // log2(e)
#define L2E2 2.8853900817779268f   // 2*log2(e)

// ---------- DPP helpers ----------
template<int R>
__device__ __forceinline__ float rotf(float v) {
    return __int_as_float(__builtin_amdgcn_mov_dpp(__float_as_int(v), 0x120 + R, 0xF, 0xF, true));
}
template<int R>
__device__ __forceinline__ h2 roth(h2 v) {    // row_ror:R on a packed half2 reg
    int i;
    __builtin_memcpy(&i, &v, 4);
    i = __builtin_amdgcn_mov_dpp(i, 0x120 + R, 0xF, 0xF, true);
    h2 o;
    __builtin_memcpy(&o, &i, 4);
    return o;
}
__device__ __forceinline__ float qxor1(float v) {  // quad_perm [1,0,3,2]
    return __int_as_float(__builtin_amdgcn_mov_dpp(__float_as_int(v), 0xB1, 0xF, 0xF, true));
}
__device__ __forceinline__ float qxor2(float v) {  // quad_perm [2,3,0,1]
    return __int_as_float(__builtin_amdgcn_mov_dpp(__float_as_int(v), 0x4E, 0xF, 0xF, true));
}
__device__ __forceinline__ float qxor3(float v) {  // quad_perm [3,2,1,0]
    return __int_as_float(__builtin_amdgcn_mov_dpp(__float_as_int(v), 0x1B, 0xF, 0xF, true));
}

__device__ __forceinline__ float fex2(float x) { return __builtin_amdgcn_exp2f(x); }
__device__ __forceinline__ float frcp(float x) { return __builtin_amdgcn_rcpf(x); }
// pre-scaled sigmoid: x already multiplied by log2(e) (folded into weights)
__device__ __forceinline__ float fsig2(float x) { return frcp(1.0f + fex2(-x)); }
__device__ __forceinline__ float4 ld4(const float* p) { return *(const float4*)p; }

// Pack two f32 to half2 via v_cvt_pkrtz_f16_f32.
__device__ __forceinline__ h2 pkh(float a, float b) {
    auto t = __builtin_amdgcn_cvt_pkrtz(a, b);
    h2 o;
    __builtin_memcpy(&o, &t, 4);
    return o;
}

// Half-broadcast-exchange (lanes i <-> i+32): after call lo = lower half's
// value everywhere, hi = upper half's value everywhere. (semantics HW-verified)
__device__ __forceinline__ void bcast32(float v, float& lo, float& hi) {
    lo = v;
    asm("v_permlane32_swap_b32 %0, %1" : "+v"(lo), "+v"(v));
    hi = v;
}
// Row-pair broadcast-exchange (lanes i <-> i+16 within each half):
// e = even-row's value in both rows of the pair, o = odd-row's value.
__device__ __forceinline__ void bcast16(float v, float& e, float& o) {
    e = v;
    asm("v_permlane16_swap_b32 %0, %1" : "+v"(e), "+v"(v));
    o = v;
}

// hp[k] = packed (h[(j+sgn*2k)&15], h[(j+sgn*(2k+1))&15]) as half2.
#define FILL_HP16(hp, h)                                      \
    do {                                                      \
        h2 p0_ = pkh((h), rotf<1>(h));                        \
        hp[0] = p0_;                                          \
        hp[1] = roth<2>(p0_);                                 \
        hp[2] = roth<4>(p0_);                                 \
        hp[3] = roth<6>(p0_);                                 \
        hp[4] = roth<8>(p0_);                                 \
        hp[5] = roth<10>(p0_);                                \
        hp[6] = roth<12>(p0_);                                \
        hp[7] = roth<14>(p0_);                                \
    } while (0)

// single-chain dots (no final add; depth is free under issue-cadence bound)
__device__ __forceinline__ float dot8s(const h2* __restrict__ w, const h2* hp, float start) {
    float a = start;
#pragma unroll
    for (int p = 0; p < 8; ++p) a = __builtin_amdgcn_fdot2(w[p], hp[p], a, false);
    return a;
}
__device__ __forceinline__ float dot10s(const h2* __restrict__ w, const h2* hp, float start) {
    float a = start;
#pragma unroll
    for (int p = 0; p < 10; ++p) a = __builtin_amdgcn_fdot2(w[p], hp[p], a, false);
    return a;
}

// ======================= FUSED ENC+DEC, 1 element/wave, 4 roles =======================
// 512 blocks x 64 threads. Each 16-lane row computes ONE dot per step.
// Role order chosen so bcast16 delivers the shared-sigmoid input directly:
//   enc rows: 0 = r' (h+x, L2E)   1 = hn (h, L2E2)   2 = z' (h+x, L2E)  3 = inn (x, L2E2)
//   dec rows: 0 = r' (h, L2E)     1 = hn (h, L2E2)   2 = z' (h, L2E)    3 = oa (oW, exact)
// bcast16 -> e = {r' | z'} per half, o = {hn | inn-or-oa}; one fsig2 covers r AND z.
__global__ __launch_bounds__(64, 1) void rnn_kernel(
    const float* __restrict__ gt,
    const float* __restrict__ eWih, const float* __restrict__ eWhh,
    const float* __restrict__ ebih, const float* __restrict__ ebhh,
    const float* __restrict__ dWih, const float* __restrict__ dWhh,
    const float* __restrict__ dbih, const float* __restrict__ dbhh,
    const float* __restrict__ oW,  const float* __restrict__ ob,
    float* __restrict__ outs)                 // [NB][S_LEN][4] logit scratch
{
    const int lane = threadIdx.x;
    const int j    = lane & 15;
    const int q    = j & 3;
    const int row  = lane >> 4;               // 0..3 = gate role
    const bool loH = (lane < 32);
    const int b    = blockIdx.x;

    int probe = __builtin_amdgcn_mov_dpp(j, 0x121, 0xF, 0xF, true);
    const int sgn = (probe == ((j + 1) & 15)) ? 1 : -1;

    float h = 0.0f;

    // ---------------- encoder phase ----------------
    {
        const float* gb = gt + (size_t)b * (NV * S_LEN);
        h2 w[10];
        float start;
        {
            // h-part rows of this role's weight matrix (zero for row3)
            const int g  = (row == 0) ? 0 : (row == 2) ? 1 : 2;   // r,z,n row-block in Whh/Wih
            const float schh = (row == 0 || row == 2) ? L2E : (row == 1 ? L2E2 : 0.0f);
            const float scih = (row == 0 || row == 2) ? L2E : (row == 3 ? L2E2 : 0.0f);
#pragma unroll
            for (int p = 0; p < 8; ++p) {
                int k0 = (j + sgn * (2 * p)) & 15;
                int k1 = (j + sgn * (2 * p + 1)) & 15;
                w[p] = (h2){(_Float16)(schh * eWhh[(g * NH + j) * NH + k0]),
                            (_Float16)(schh * eWhh[(g * NH + j) * NH + k1])};
            }
#pragma unroll
            for (int p = 0; p < 2; ++p) {     // x-part, k16-19 (zero for row1)
                w[8 + p] = (h2){(_Float16)(scih * eWih[(g * NH + j) * NV + 2 * p]),
                                (_Float16)(scih * eWih[(g * NH + j) * NV + 2 * p + 1])};
            }
            start = (row == 0) ? L2E  * (ebih[j] + ebhh[j])
                  : (row == 2) ? L2E  * (ebih[NH + j] + ebhh[NH + j])
                  : (row == 1) ? L2E2 * ebhh[2 * NH + j]
                               : L2E2 * ebih[2 * NH + j];
        }

        auto estep = [&](float x0, float x1, float x2, float x3) {
            h2 hp[10];
            FILL_HP16(hp, h);
            hp[8] = pkh(x0, x1);
            hp[9] = pkh(x2, x3);
            float v = dot10s(w, hp, start);
            float e, o_;
            bcast16(v, e, o_);                 // e = {r'|z'}, o_ = {hn|inn}
            float hn_, inn_;
            bcast32(o_, hn_, inn_);
            float sg = fsig2(e);               // lo: r, hi: z (shared trans)
            float r, z;
            bcast32(sg, r, z);
            float y  = fmaf(r, hn_, inn_);     // = 2*log2(e) * (inn + r*hn)
            float w2 = fsig2(y);               // = sigma(2y) -> tanh blend
            float t2 = fmaf(-2.0f, z, 2.0f);
            float tb = fmaf(z, h, z - 1.0f);
            h = fmaf(w2, t2, tb);
        };

        float4 A0 = ld4(gb + 0 * S_LEN), A1 = ld4(gb + 1 * S_LEN),
               A2 = ld4(gb + 2 * S_LEN), A3 = ld4(gb + 3 * S_LEN);
        float4 B0 = ld4(gb + 0 * S_LEN + 4), B1 = ld4(gb + 1 * S_LEN + 4),
               B2 = ld4(gb + 2 * S_LEN + 4), B3 = ld4(gb + 3 * S_LEN + 4);
        for (int t = 0; t < S_LEN; t += 8) {
            estep(A0.x, A1.x, A2.x, A3.x);
            estep(A0.y, A1.y, A2.y, A3.y);
            estep(A0.z, A1.z, A2.z, A3.z);
            estep(A0.w, A1.w, A2.w, A3.w);
            int ta = t + 8;  if (ta > S_LEN - 4) ta = S_LEN - 4;
            A0 = ld4(gb + 0 * S_LEN + ta); A1 = ld4(gb + 1 * S_LEN + ta);
            A2 = ld4(gb + 2 * S_LEN + ta); A3 = ld4(gb + 3 * S_LEN + ta);
            estep(B0.x, B1.x, B2.x, B3.x);
            estep(B0.y, B1.y, B2.y, B3.y);
            estep(B0.z, B1.z, B2.z, B3.z);
            estep(B0.w, B1.w, B2.w, B3.w);
            int tb2 = t + 12; if (tb2 > S_LEN - 4) tb2 = S_LEN - 4;
            B0 = ld4(gb + 0 * S_LEN + tb2); B1 = ld4(gb + 1 * S_LEN + tb2);
            B2 = ld4(gb + 2 * S_LEN + tb2); B3 = ld4(gb + 3 * S_LEN + tb2);
        }
    }

    // ---------------- decoder phase ----------------
    h2 w[8];
    float start;
    {
        const int g  = (row == 0) ? 0 : (row == 2) ? 1 : 2;
        const float schh = (row == 0 || row == 2) ? L2E : (row == 1 ? L2E2 : 0.0f);
#pragma unroll
        for (int p = 0; p < 8; ++p) {
            int k0 = (j + sgn * (2 * p)) & 15;
            int k1 = (j + sgn * (2 * p + 1)) & 15;
            float w0 = (row == 3) ? oW[q * NH + k0] : schh * dWhh[(g * NH + j) * NH + k0];
            float w1 = (row == 3) ? oW[q * NH + k1] : schh * dWhh[(g * NH + j) * NH + k1];
            w[p] = (h2){(_Float16)w0, (_Float16)w1};
        }
        start = (row == 0) ? L2E  * (dbih[j] + dbhh[j])
              : (row == 2) ? L2E  * (dbih[NH + j] + dbhh[NH + j])
              : (row == 1) ? L2E2 * dbhh[2 * NH + j]
                           : ob[q];
    }
    const float bNi  = dbih[2 * NH + j];
    const float bNiS = L2E2 * bNi;
    // per-class one-hot x-terms, REGISTER order m (class = m ^ q), pre-scaled.
    // SA: lo-half = r-gate x-terms, hi-half = z-gate x-terms (sig sharing).
    const int gS = loH ? 0 : 1;
    float SA[NV], KN[NV];
#pragma unroll
    for (int m = 0; m < NV; ++m) {
        int c = m ^ q;
        SA[m] = L2E * dWih[(gS * NH + j) * NV + c];
        KN[m] = L2E2 * (bNi + dWih[(2 * NH + j) * NV + c]);
    }

    int oidx = (b << 15) + q;                 // (b*S_LEN + 0)*4 + q
    const bool storer = (lane < 4);           // row0 quad0: q = lane

    // koff is a compile-time literal under #pragma unroll: store address folds
    // into the global_store immediate offset (one oidx add per 8 steps).
    auto dstep = [&](int koff) {
        h2 hp[8];
        FILL_HP16(hp, h);
        float v = dot8s(w, hp, start);
        float e, o_;
        bcast16(v, e, o_);                    // e = {r'|z'}, o_ = {hn|oa}
        float hn_, oa;
        bcast32(o_, hn_, oa);
        if (storer) outs[oidx + koff] = oa;   // logits of step t-1
        // argmax over the quad: 3 independent DPP fetches
        float ob_ = qxor1(oa);                // out[q^1]
        float oc_ = qxor2(oa);                // out[q^2]
        float od_ = qxor3(oa);                // out[q^3]
        bool cA = ob_ > oa;  float mA = fmaxf(oa, ob_);
        bool cB = od_ > oc_; float mB = fmaxf(oc_, od_);
        bool hi_ = mB > mA;
        float KA  = hi_ ? (cB ? SA[3] : SA[2]) : (cA ? SA[1] : SA[0]);
        float KN_ = hi_ ? (cB ? KN[3] : KN[2]) : (cA ? KN[1] : KN[0]);
        float sg  = fsig2(e + KA);            // lo: r, hi: z (shared trans)
        float r, z;
        bcast32(sg, r, z);
        float y   = fmaf(r, hn_, KN_);
        float w2  = fsig2(y);
        float t2  = fmaf(-2.0f, z, 2.0f);
        float tb  = fmaf(z, h, z - 1.0f);
        h = fmaf(w2, t2, tb);
    };

    // t = 0: x0 = zeros — no K terms, no store, no argmax
    {
        h2 hp[8];
        FILL_HP16(hp, h);
        float v = dot8s(w, hp, start);
        float e, o_;
        bcast16(v, e, o_);
        float hn_, oa;
        bcast32(o_, hn_, oa);
        float sg = fsig2(e);
        float r, z;
        bcast32(sg, r, z);
        float y  = fmaf(r, hn_, bNiS);
        float w2 = fsig2(y);
        float t2 = fmaf(-2.0f, z, 2.0f);
        float tb = fmaf(z, h, z - 1.0f);
        h = fmaf(w2, t2, tb);
    }
    // t = 1..8191: 8191 dsteps = 1023 x 8 + 7
    for (int u = 0; u < 8184; u += 8) {
#pragma unroll
        for (int k = 0; k < 8; ++k) dstep(k * 4);
        oidx += 32;
    }
#pragma unroll
    for (int k = 0; k < 7; ++k) dstep(k * 4);
    oidx += 28;

    // tail: logits of final step (t = S-1)
    {
        h2 hp[8];
        FILL_HP16(hp, h);
        float v = dot8s(w, hp, start);
        float e, o_;
        bcast16(v, e, o_);
        float hn_, oa;
        bcast32(o_, hn_, oa);
        if (storer) outs[oidx] = oa;
    }
}

// Epilogue: NLL over all (b,t) from stored logits + gt targets; zero the scratch.
__global__ __launch_bounds__(1024) void loss_kernel(
    const float* __restrict__ gt, float* __restrict__ outs, float* __restrict__ loss)
{
    int tid = blockIdx.x * 1024 + threadIdx.x;   // over NB*S_LEN
    int t = tid & (S_LEN - 1);
    int b = tid >> 13;
    float4 o = *(const float4*)(outs + (size_t)tid * 4);
    const float* g = gt + (size_t)b * (NV * S_LEN) + t;
    float p0 = g[0], p1 = g[S_LEN], p2 = g[2 * S_LEN], p3 = g[3 * S_LEN];
    int tg = (p1 > p0) ? 1 : 0;  float bm = fmaxf(p0, p1);
    tg = (p2 > bm) ? 2 : tg;     bm = fmaxf(p2, bm);
    tg = (p3 > bm) ? 3 : tg;
    float vt = (tg & 1) ? ((tg & 2) ? o.w : o.y) : ((tg & 2) ? o.z : o.x);
    float mx = fmaxf(fmaxf(o.x, o.y), fmaxf(o.z, o.w));
    float ss = __expf(o.x - mx) + __expf(o.y - mx) + __expf(o.z - mx) + __expf(o.w - mx);
    float v  = (mx - vt) + __logf(ss);
    *(float4*)(outs + (size_t)tid * 4) = make_float4(0.f, 0.f, 0.f, 0.f);
#pragma unroll
    for (int d = 1; d < 64; d <<= 1) v += __shfl_xor(v, d, 64);
    __shared__ float sm[16];
    int w = threadIdx.x >> 6;
    if ((threadIdx.x & 63) == 0) sm[w] = v;
    __syncthreads();
    if (threadIdx.x < 16) {
        float s = sm[threadIdx.x];
#pragma unroll
        for (int d = 1; d < 16; d <<= 1) s += __shfl_xor(s, d, 64);
        if (threadIdx.x == 0) atomicAdd(loss, s * (1.0f / NB));
    }
}

extern "C" void kernel_launch(void* const* d_in, const int* in_sizes, int n_in,
                              void* d_out, int out_size, void* d_ws, size_t ws_size,
                              hipStream_t stream) {
    (void)in_sizes; (void)n_in; (void)d_ws; (void)ws_size; (void)out_size;
    const float* gt   = (const float*)d_in[0];
    const float* eWih = (const float*)d_in[1];
    const float* eWhh = (const float*)d_in[2];
    const float* ebih = (const float*)d_in[3];
    const float* ebhh = (const float*)d_in[4];
    const float* dWih = (const float*)d_in[5];
    const float* dWhh = (const float*)d_in[6];
    const float* dbih = (const float*)d_in[7];
    const float* dbhh = (const float*)d_in[8];
    const float* oW   = (const float*)d_in[9];
    const float* ob   = (const float*)d_in[10];

    float* out  = (float*)d_out;       // out[0] = loss
    float* outs = out + 1;             // [NB][S_LEN][4] logit scratch == output_batch region
    (void)hipMemsetAsync(d_out, 0, sizeof(float), stream);   // zero loss only
    rnn_kernel<<<NB, 64, 0, stream>>>(gt, eWih, eWhh, ebih, ebhh,
                                      dWih, dWhh, dbih, dbhh, oW, ob, outs);
    loss_kernel<<<(NB * S_LEN) / 1024, 1024, 0, stream>>>(gt, outs, out);
}